// Round 6
// baseline (870.357 us; speedup 1.0000x reference)
//
#include <hip/hip_runtime.h>

namespace {

constexpr int Cn   = 256;
constexpr int Hh   = 128;
constexpr int Ww   = 128;
constexpr int HW   = Hh * Ww;
constexpr int TW   = 16;              // tile width
constexpr int TH   = 8;               // tile height
constexpr int CCH  = 8;               // channels per LDS chunk
constexpr int NCH  = Cn / CCH;        // 32 chunks
constexpr int HALO = 4;
constexpr int SR   = TH + 2 * HALO;   // 16 staged rows
constexpr int SC   = TW + 2 * HALO;   // 24 staged cols
constexpr int SS   = 28;              // padded row stride (floats) = 7 granules (odd)
constexpr int SCH  = SR * SS;         // 448 floats per channel (112 granules, %8==0)
constexpr int NOFF = 81;
constexpr int STG  = CCH * SR * SC;   // 3072 staged elements per chunk

// Block: 576 threads = 9 waves; wave wv <-> window row di = wv (exact split,
// o = 9*wv + dj). Lane l: h = l&7 (tile row), m = (l>>3)&1 (px cols 8m..8m+7),
// c4 = l>>4 (4-way channel split, shuffle-reduced at epilogue).
// h in the LOW lane bits => every 8-lane b128 phase hits 8 distinct 16B
// granule slots (stride 7 granules, odd) => conflict-free LDS reads.

__global__ __launch_bounds__(576, 5)
void costvol_kernel(const float* __restrict__ x1,
                    const float* __restrict__ x2,
                    float* __restrict__ out)
{
  __shared__ float s2[2][CCH * SCH];   // 28,672 B

  const int t  = threadIdx.x;
  const int wv = t >> 6;               // di = 0..8
  const int l  = t & 63;
  const int h  = l & 7;                // tile row 0..7
  const int m  = (l >> 3) & 1;         // px group
  const int c4 = l >> 4;               // channel sub-lane 0..3

  const int x0 = blockIdx.x * TW;
  const int y0 = blockIdx.y * TH;
  const int b  = blockIdx.z;

  // x1: this lane's 8 pixels of row (y0+h), channel c = 4*sg + c4
  const float* g1 = x1 + (size_t)b * Cn * HW + (size_t)(y0 + h) * Ww + (x0 + 8 * m);
  const float* g2 = x2 + (size_t)b * Cn * HW;

  // ---- x2 staging map: thread stages elements e = t + 576*j, j=0..5 ----
  int  soff[6], swr[6];
  bool sval[6], sok[6];
#pragma unroll
  for (int j = 0; j < 6; ++j) {
    const int e   = t + 576 * j;
    const bool e_ok = (e < STG);
    const int ch  = e / (SR * SC);
    const int rem = e % (SR * SC);
    const int row = rem / SC, col = rem % SC;
    const int gy = y0 - HALO + row, gx = x0 - HALO + col;
    const bool ok = e_ok && ((unsigned)gy < (unsigned)Hh) && ((unsigned)gx < (unsigned)Ww);
    sok[j]  = e_ok;
    sval[j] = ok;
    soff[j] = ok ? (ch * HW + gy * Ww + gx) : 0;
    swr[j]  = e_ok ? (ch * SCH + row * SS + col) : 0;
  }

  float rs[6];
  auto stage_load = [&](int k) {
    const size_t cb = (size_t)(k * CCH) * HW;
#pragma unroll
    for (int j = 0; j < 6; ++j)
      rs[j] = sval[j] ? g2[cb + soff[j]] : 0.0f;
  };
  auto stage_write = [&](int nb) {
    float* s = s2[nb];
#pragma unroll
    for (int j = 0; j < 6; ++j)
      if (sok[j]) s[swr[j]] = rs[j];
  };

  float acc[9][8];
#pragma unroll
  for (int d = 0; d < 9; ++d)
#pragma unroll
    for (int p = 0; p < 8; ++p) acc[d][p] = 0.0f;

  const int rbase = (h + wv) * SS + 8 * m;   // lane's window row base (floats)

  // prefetch x1 for step sg=0 (channel c4)
  float4 a0c = *reinterpret_cast<const float4*>(g1 + (size_t)c4 * HW);
  float4 a1c = *reinterpret_cast<const float4*>(g1 + (size_t)c4 * HW + 4);

  stage_load(0);
  stage_write(0);
  __syncthreads();

  for (int k = 0; k < NCH; ++k) {
    if (k + 1 < NCH) stage_load(k + 1);              // issue early (T14)
    const float* sc = s2[k & 1];
#pragma unroll
    for (int s = 0; s < 2; ++s) {
      const int sg = 2 * k + s;
      float4 a0n = {0, 0, 0, 0}, a1n = {0, 0, 0, 0};
      if (sg + 1 < Cn / 4) {                         // prefetch next step's x1
        const size_t c = (size_t)(4 * (sg + 1) + c4) * HW;
        a0n = *reinterpret_cast<const float4*>(g1 + c);
        a1n = *reinterpret_cast<const float4*>(g1 + c + 4);
      }
      const float* bp = sc + (4 * s + c4) * SCH + rbase;
      float w[16];
      *reinterpret_cast<float4*>(w)      = *reinterpret_cast<const float4*>(bp);
      *reinterpret_cast<float4*>(w + 4)  = *reinterpret_cast<const float4*>(bp + 4);
      *reinterpret_cast<float4*>(w + 8)  = *reinterpret_cast<const float4*>(bp + 8);
      *reinterpret_cast<float4*>(w + 12) = *reinterpret_cast<const float4*>(bp + 12);
      const float av[8] = {a0c.x, a0c.y, a0c.z, a0c.w, a1c.x, a1c.y, a1c.z, a1c.w};
#pragma unroll
      for (int dj = 0; dj < 9; ++dj)
#pragma unroll
        for (int p = 0; p < 8; ++p)
          acc[dj][p] = fmaf(av[p], w[p + dj], acc[dj][p]);
      a0c = a0n; a1c = a1n;
    }
    if (k + 1 < NCH) stage_write((k + 1) & 1);       // write late
    __syncthreads();
  }

  // ---- epilogue: reduce 4-way channel split (lanes l, l+16, l+32, l+48) ----
#pragma unroll
  for (int dj = 0; dj < 9; ++dj)
#pragma unroll
    for (int p = 0; p < 8; ++p) {
      float v = acc[dj][p];
      v += __shfl_down(v, 32);
      v += __shfl_down(v, 16);
      acc[dj][p] = v;
    }

  if (l < 16) {                                      // h = l&7, m = (l>>3)&1
    const float invc = 1.0f / (float)Cn;
    const int y  = y0 + h;
    const int xb = x0 + 8 * m;
#pragma unroll
    for (int dj = 0; dj < 9; ++dj) {
      const int o = wv * 9 + dj;
      float* op = out + (((size_t)b * NOFF + o) * Hh + y) * Ww + xb;
      float4 v0, v1;
      v0.x = acc[dj][0] * invc; v0.y = acc[dj][1] * invc;
      v0.z = acc[dj][2] * invc; v0.w = acc[dj][3] * invc;
      v1.x = acc[dj][4] * invc; v1.y = acc[dj][5] * invc;
      v1.z = acc[dj][6] * invc; v1.w = acc[dj][7] * invc;
      *reinterpret_cast<float4*>(op)     = v0;
      *reinterpret_cast<float4*>(op + 4) = v1;
    }
  }
}

} // namespace

extern "C" void kernel_launch(void* const* d_in, const int* in_sizes, int n_in,
                              void* d_out, int out_size, void* d_ws, size_t ws_size,
                              hipStream_t stream) {
  const float* x1 = (const float*)d_in[0];
  const float* x2 = (const float*)d_in[1];
  float* out = (float*)d_out;

  dim3 grid(Ww / TW, Hh / TH, 4);   // 8 x 16 x 4 = 512 blocks (2 per CU)
  dim3 block(576);                  // 9 waves: wave wv <-> window row di
  costvol_kernel<<<grid, block, 0, stream>>>(x1, x2, out);
}

// Round 7
// 127.869 us; speedup vs baseline: 6.8066x; 6.8066x over previous
//
#include <hip/hip_runtime.h>

namespace {

constexpr int Cn   = 256;
constexpr int Hh   = 128;
constexpr int Ww   = 128;
constexpr int HW   = Hh * Ww;
constexpr int TW   = 16;              // tile width
constexpr int TH   = 8;               // tile height
constexpr int CCH  = 8;               // channels per LDS chunk
constexpr int NCH  = Cn / CCH;        // 32 chunks
constexpr int HALO = 4;
constexpr int SR   = TH + 2 * HALO;   // 16 staged rows
constexpr int SC   = TW + 2 * HALO;   // 24 staged cols
constexpr int SS   = 28;              // padded row stride (floats) = 7 granules (odd)
constexpr int SCH  = SR * SS;         // 448 floats per channel (112 granules, %8==0)
constexpr int NOFF = 81;
constexpr int STG  = CCH * SR * SC;   // 3072 staged elements per chunk

// Block: 576 threads = 9 waves; wave wv <-> window row di = wv (exact split,
// o = 9*wv + dj). Lane l: h = l&7 (tile row), m = (l>>3)&1 (px cols 8m..8m+7),
// c4 = l>>4 (4-way channel split, shuffle-reduced at epilogue).
// h in the LOW lane bits => every 8-lane b128 phase hits 8 distinct 16B
// granule slots (stride 7 granules, odd; per-channel region 112 granules %8==0)
// => conflict-free LDS reads.

__global__ __launch_bounds__(576, 2)   // cap 256 VGPR: round-6's (,5) forced a
                                       // 72-reg acc spill (WRITE_SIZE 1.8 GB)
void costvol_kernel(const float* __restrict__ x1,
                    const float* __restrict__ x2,
                    float* __restrict__ out)
{
  __shared__ float s2[2][CCH * SCH];   // 28,672 B

  const int t  = threadIdx.x;
  const int wv = t >> 6;               // di = 0..8
  const int l  = t & 63;
  const int h  = l & 7;                // tile row 0..7
  const int m  = (l >> 3) & 1;         // px group
  const int c4 = l >> 4;               // channel sub-lane 0..3

  const int x0 = blockIdx.x * TW;
  const int y0 = blockIdx.y * TH;
  const int b  = blockIdx.z;

  // x1: this lane's 8 pixels of row (y0+h), channel c = 4*sg + c4.
  // Same address for all 9 waves -> L1-broadcast; no reg prefetch needed.
  const float* g1 = x1 + (size_t)b * Cn * HW + (size_t)(y0 + h) * Ww + (x0 + 8 * m);
  const float* g2 = x2 + (size_t)b * Cn * HW;

  // ---- x2 staging map: thread stages elements e = t + 576*j, j=0..5 ----
  int  soff[6], swr[6];
  bool sval[6], sok[6];
#pragma unroll
  for (int j = 0; j < 6; ++j) {
    const int e   = t + 576 * j;
    const bool e_ok = (e < STG);
    const int ch  = e / (SR * SC);
    const int rem = e % (SR * SC);
    const int row = rem / SC, col = rem % SC;
    const int gy = y0 - HALO + row, gx = x0 - HALO + col;
    const bool ok = e_ok && ((unsigned)gy < (unsigned)Hh) && ((unsigned)gx < (unsigned)Ww);
    sok[j]  = e_ok;
    sval[j] = ok;
    soff[j] = ok ? (ch * HW + gy * Ww + gx) : 0;
    swr[j]  = e_ok ? (ch * SCH + row * SS + col) : 0;
  }

  float rs[6];
  auto stage_load = [&](int k) {
    const size_t cb = (size_t)(k * CCH) * HW;
#pragma unroll
    for (int j = 0; j < 6; ++j)
      rs[j] = sval[j] ? g2[cb + soff[j]] : 0.0f;
  };
  auto stage_write = [&](int nb) {
    float* s = s2[nb];
#pragma unroll
    for (int j = 0; j < 6; ++j)
      if (sok[j]) s[swr[j]] = rs[j];
  };

  float acc[9][8];
#pragma unroll
  for (int d = 0; d < 9; ++d)
#pragma unroll
    for (int p = 0; p < 8; ++p) acc[d][p] = 0.0f;

  const int rbase = (h + wv) * SS + 8 * m;   // lane's window row base (floats)

  stage_load(0);
  stage_write(0);
  __syncthreads();

  for (int k = 0; k < NCH; ++k) {
    if (k + 1 < NCH) stage_load(k + 1);              // issue early (T14)
    const float* sc = s2[k & 1];
#pragma unroll
    for (int s = 0; s < 2; ++s) {
      const size_t c = (size_t)(4 * (2 * k + s) + c4) * HW;
      const float4 a0 = *reinterpret_cast<const float4*>(g1 + c);
      const float4 a1 = *reinterpret_cast<const float4*>(g1 + c + 4);
      const float* bp = sc + (4 * s + c4) * SCH + rbase;
      float w[16];
      *reinterpret_cast<float4*>(w)      = *reinterpret_cast<const float4*>(bp);
      *reinterpret_cast<float4*>(w + 4)  = *reinterpret_cast<const float4*>(bp + 4);
      *reinterpret_cast<float4*>(w + 8)  = *reinterpret_cast<const float4*>(bp + 8);
      *reinterpret_cast<float4*>(w + 12) = *reinterpret_cast<const float4*>(bp + 12);
      const float av[8] = {a0.x, a0.y, a0.z, a0.w, a1.x, a1.y, a1.z, a1.w};
#pragma unroll
      for (int dj = 0; dj < 9; ++dj)
#pragma unroll
        for (int p = 0; p < 8; ++p)
          acc[dj][p] = fmaf(av[p], w[p + dj], acc[dj][p]);
    }
    if (k + 1 < NCH) stage_write((k + 1) & 1);       // write late
    __syncthreads();
  }

  // ---- epilogue: reduce 4-way channel split (lanes l, l+16, l+32, l+48) ----
#pragma unroll
  for (int dj = 0; dj < 9; ++dj)
#pragma unroll
    for (int p = 0; p < 8; ++p) {
      float v = acc[dj][p];
      v += __shfl_down(v, 32);
      v += __shfl_down(v, 16);
      acc[dj][p] = v;
    }

  if (l < 16) {                                      // h = l&7, m = (l>>3)&1
    const float invc = 1.0f / (float)Cn;
    const int y  = y0 + h;
    const int xb = x0 + 8 * m;
#pragma unroll
    for (int dj = 0; dj < 9; ++dj) {
      const int o = wv * 9 + dj;
      float* op = out + (((size_t)b * NOFF + o) * Hh + y) * Ww + xb;
      float4 v0, v1;
      v0.x = acc[dj][0] * invc; v0.y = acc[dj][1] * invc;
      v0.z = acc[dj][2] * invc; v0.w = acc[dj][3] * invc;
      v1.x = acc[dj][4] * invc; v1.y = acc[dj][5] * invc;
      v1.z = acc[dj][6] * invc; v1.w = acc[dj][7] * invc;
      *reinterpret_cast<float4*>(op)     = v0;
      *reinterpret_cast<float4*>(op + 4) = v1;
    }
  }
}

} // namespace

extern "C" void kernel_launch(void* const* d_in, const int* in_sizes, int n_in,
                              void* d_out, int out_size, void* d_ws, size_t ws_size,
                              hipStream_t stream) {
  const float* x1 = (const float*)d_in[0];
  const float* x2 = (const float*)d_in[1];
  float* out = (float*)d_out;

  dim3 grid(Ww / TW, Hh / TH, 4);   // 8 x 16 x 4 = 512 blocks
  dim3 block(576);                  // 9 waves: wave wv <-> window row di
  costvol_kernel<<<grid, block, 0, stream>>>(x1, x2, out);
}